// Round 1
// baseline (547.999 us; speedup 1.0000x reference)
//
#include <hip/hip_runtime.h>

#define NODE_DIM 128
#define NUM_IRREPS 224
#define SPH_DIM 480
#define HIDDEN 576   // NODE_DIM + 2*NUM_IRREPS
#define NUM_BASIS 20
#define N_NODES 10000
#define N_EDGES 160000
#define NPB 4        // nodes per block in node MLP

// ---------------- init: d_out = concat(x_scalar, x_spherical) ----------------
__global__ void init_out(const float* __restrict__ xs,
                         const float* __restrict__ xsp,
                         float* __restrict__ out) {
    const int stride = gridDim.x * blockDim.x;
    const int t0 = blockIdx.x * blockDim.x + threadIdx.x;
    for (int i = t0; i < N_NODES * NODE_DIM; i += stride) out[i] = xs[i];
    float* o2 = out + (size_t)N_NODES * NODE_DIM;
    for (int i = t0; i < N_NODES * SPH_DIM; i += stride) o2[i] = xsp[i];
}

// ---------------- node MLP: scalar_out = silu(x@W1+b1)@W2+b2 ----------------
__global__ __launch_bounds__(128) void node_mlp(
    const float* __restrict__ x,
    const float* __restrict__ W1, const float* __restrict__ b1,
    const float* __restrict__ W2, const float* __restrict__ b2,
    float* __restrict__ so) {
    __shared__ float xs[NPB][NODE_DIM];
    __shared__ float hs[NPB][NODE_DIM];
    const int tid = threadIdx.x;
    const int n0 = blockIdx.x * NPB;

    #pragma unroll
    for (int n = 0; n < NPB; ++n) {
        int node = n0 + n;
        xs[n][tid] = (node < N_NODES) ? x[(size_t)node * NODE_DIM + tid] : 0.f;
    }
    __syncthreads();

    // h = silu(x @ W1 + b1); thread tid owns column tid
    float acc[NPB];
    #pragma unroll
    for (int n = 0; n < NPB; ++n) acc[n] = b1[tid];
    for (int k = 0; k < NODE_DIM; ++k) {
        float w = W1[k * NODE_DIM + tid];
        #pragma unroll
        for (int n = 0; n < NPB; ++n) acc[n] = fmaf(xs[n][k], w, acc[n]);
    }
    #pragma unroll
    for (int n = 0; n < NPB; ++n) {
        float v = acc[n];
        hs[n][tid] = v / (1.f + __expf(-v));
    }
    __syncthreads();

    // scalar_out = h @ W2 + b2 ; 576 columns, thread strides by 128
    for (int j = tid; j < HIDDEN; j += 128) {
        float a2[NPB];
        #pragma unroll
        for (int n = 0; n < NPB; ++n) a2[n] = b2[j];
        for (int k = 0; k < NODE_DIM; ++k) {
            float w = W2[k * HIDDEN + j];
            #pragma unroll
            for (int n = 0; n < NPB; ++n) a2[n] = fmaf(hs[n][k], w, a2[n]);
        }
        #pragma unroll
        for (int n = 0; n < NPB; ++n) {
            int node = n0 + n;
            if (node < N_NODES) so[(size_t)node * HIDDEN + j] = a2[n];
        }
    }
}

// ---------------- per-edge filter + gated message + scatter-add ----------------
__global__ __launch_bounds__(128) void edge_kernel(
    const float* __restrict__ xsp,
    const float* __restrict__ rbf, const float* __restrict__ fcut,
    const float* __restrict__ rsh, const int* __restrict__ eidx,
    const float* __restrict__ Wr, const float* __restrict__ br,
    const float* __restrict__ so,
    float* __restrict__ out_scalar, float* __restrict__ out_sph) {
    __shared__ float rbf_s[NUM_BASIS];
    __shared__ float fo[HIDDEN];
    __shared__ float fc_s;
    const int e = blockIdx.x;
    const int tid = threadIdx.x;

    if (tid < NUM_BASIS) rbf_s[tid] = rbf[(size_t)e * NUM_BASIS + tid];
    if (tid == NUM_BASIS) fc_s = fcut[e];
    const int src = eidx[e];
    const int dst = eidx[N_EDGES + e];
    __syncthreads();

    const float fc = fc_s;
    // filter_out[j] = (rbf@Wr + br)[j] * fcut * scalar_out[dst][j]
    for (int j = tid; j < HIDDEN; j += 128) {
        float acc = br[j];
        #pragma unroll
        for (int k = 0; k < NUM_BASIS; ++k)
            acc = fmaf(rbf_s[k], Wr[k * HIDDEN + j], acc);
        fo[j] = acc * fc * so[(size_t)dst * HIDDEN + j];
    }
    __syncthreads();

    // scalar message: filter_out[:, 448:576]
    atomicAdd(&out_scalar[(size_t)src * NODE_DIM + tid], fo[2 * NUM_IRREPS + tid]);

    // spherical message with gate expansion [1]*128 + [3]*64 + [5]*32
    for (int d = tid; d < SPH_DIM; d += 128) {
        int g;
        if (d < 128)      g = d;
        else if (d < 320) g = 128 + (d - 128) / 3;
        else              g = 192 + (d - 320) / 5;
        float ms = xsp[(size_t)dst * SPH_DIM + d] * fo[g]
                 + rsh[(size_t)e * SPH_DIM + d] * fo[NUM_IRREPS + g];
        atomicAdd(&out_sph[(size_t)src * SPH_DIM + d], ms);
    }
}

extern "C" void kernel_launch(void* const* d_in, const int* in_sizes, int n_in,
                              void* d_out, int out_size, void* d_ws, size_t ws_size,
                              hipStream_t stream) {
    const float* x_scalar    = (const float*)d_in[0];
    const float* x_spherical = (const float*)d_in[1];
    const float* rbf         = (const float*)d_in[2];
    const float* fcut        = (const float*)d_in[3];
    const float* rsh         = (const float*)d_in[4];
    const int*   eidx        = (const int*)d_in[5];
    const float* W1          = (const float*)d_in[6];
    const float* b1          = (const float*)d_in[7];
    const float* W2          = (const float*)d_in[8];
    const float* b2          = (const float*)d_in[9];
    const float* Wr          = (const float*)d_in[10];
    const float* br          = (const float*)d_in[11];

    float* out        = (float*)d_out;
    float* out_scalar = out;                                   // (N_NODES, 128)
    float* out_sph    = out + (size_t)N_NODES * NODE_DIM;      // (N_NODES, 480)
    float* scalar_out = (float*)d_ws;                          // (N_NODES, 576)

    init_out<<<2048, 256, 0, stream>>>(x_scalar, x_spherical, out);
    node_mlp<<<(N_NODES + NPB - 1) / NPB, 128, 0, stream>>>(x_scalar, W1, b1, W2, b2, scalar_out);
    edge_kernel<<<N_EDGES, 128, 0, stream>>>(x_spherical, rbf, fcut, rsh, eidx,
                                             Wr, br, scalar_out, out_scalar, out_sph);
}

// Round 2
// 500.337 us; speedup vs baseline: 1.0953x; 1.0953x over previous
//
#include <hip/hip_runtime.h>

#define NODE_DIM 128
#define NUM_IRREPS 224
#define SPH_DIM 480
#define HIDDEN 576   // NODE_DIM + 2*NUM_IRREPS
#define NUM_BASIS 20
#define N_NODES 10000
#define N_EDGES 160000
#define NPB 4        // nodes per block in node MLP

// ---------------- init: d_out = concat(x_scalar, x_spherical); zero counts ----------------
__global__ void init_out(const float* __restrict__ xs,
                         const float* __restrict__ xsp,
                         float* __restrict__ out,
                         int* __restrict__ counts) {
    const int stride = gridDim.x * blockDim.x;
    const int t0 = blockIdx.x * blockDim.x + threadIdx.x;
    for (int i = t0; i < N_NODES * NODE_DIM; i += stride) out[i] = xs[i];
    float* o2 = out + (size_t)N_NODES * NODE_DIM;
    for (int i = t0; i < N_NODES * SPH_DIM; i += stride) o2[i] = xsp[i];
    for (int i = t0; i < N_NODES; i += stride) counts[i] = 0;
}

// ---------------- node MLP: scalar_out = silu(x@W1+b1)@W2+b2 ----------------
__global__ __launch_bounds__(128) void node_mlp(
    const float* __restrict__ x,
    const float* __restrict__ W1, const float* __restrict__ b1,
    const float* __restrict__ W2, const float* __restrict__ b2,
    float* __restrict__ so) {
    __shared__ float xs[NPB][NODE_DIM];
    __shared__ float hs[NPB][NODE_DIM];
    const int tid = threadIdx.x;
    const int n0 = blockIdx.x * NPB;

    #pragma unroll
    for (int n = 0; n < NPB; ++n) {
        int node = n0 + n;
        xs[n][tid] = (node < N_NODES) ? x[(size_t)node * NODE_DIM + tid] : 0.f;
    }
    __syncthreads();

    float acc[NPB];
    #pragma unroll
    for (int n = 0; n < NPB; ++n) acc[n] = b1[tid];
    for (int k = 0; k < NODE_DIM; ++k) {
        float w = W1[k * NODE_DIM + tid];
        #pragma unroll
        for (int n = 0; n < NPB; ++n) acc[n] = fmaf(xs[n][k], w, acc[n]);
    }
    #pragma unroll
    for (int n = 0; n < NPB; ++n) {
        float v = acc[n];
        hs[n][tid] = v / (1.f + __expf(-v));
    }
    __syncthreads();

    for (int j = tid; j < HIDDEN; j += 128) {
        float a2[NPB];
        #pragma unroll
        for (int n = 0; n < NPB; ++n) a2[n] = b2[j];
        for (int k = 0; k < NODE_DIM; ++k) {
            float w = W2[k * HIDDEN + j];
            #pragma unroll
            for (int n = 0; n < NPB; ++n) a2[n] = fmaf(hs[n][k], w, a2[n]);
        }
        #pragma unroll
        for (int n = 0; n < NPB; ++n) {
            int node = n0 + n;
            if (node < N_NODES) so[(size_t)node * HIDDEN + j] = a2[n];
        }
    }
}

// ---------------- CSR build: histogram / scan / scatter ----------------
__global__ __launch_bounds__(256) void hist_kernel(const int* __restrict__ eidx,
                                                   int* __restrict__ counts) {
    int i = blockIdx.x * blockDim.x + threadIdx.x;
    if (i < N_EDGES) atomicAdd(&counts[eidx[i]], 1);   // bucket by src = edge_index[0]
}

__global__ __launch_bounds__(1024) void scan_kernel(const int* __restrict__ counts,
                                                    int* __restrict__ offsets,
                                                    int* __restrict__ cursor) {
    __shared__ int s[1024];
    const int tid = threadIdx.x;
    int vals[10];
    int run = 0;
    #pragma unroll
    for (int i = 0; i < 10; ++i) {
        int idx = tid * 10 + i;
        int c = (idx < N_NODES) ? counts[idx] : 0;
        vals[i] = run;
        run += c;
    }
    s[tid] = run;
    __syncthreads();
    for (int off = 1; off < 1024; off <<= 1) {
        int t = (tid >= off) ? s[tid - off] : 0;
        __syncthreads();
        if (tid >= off) s[tid] += t;
        __syncthreads();
    }
    int base = (tid > 0) ? s[tid - 1] : 0;
    #pragma unroll
    for (int i = 0; i < 10; ++i) {
        int idx = tid * 10 + i;
        if (idx < N_NODES) {
            int v = base + vals[i];
            offsets[idx] = v;
            cursor[idx] = v;
        }
    }
    if (tid == 1023) offsets[N_NODES] = s[1023];
}

__global__ __launch_bounds__(256) void scatter_kernel(const int* __restrict__ eidx,
                                                      int* __restrict__ cursor,
                                                      int* __restrict__ edge_order) {
    int i = blockIdx.x * blockDim.x + threadIdx.x;
    if (i < N_EDGES) {
        int s = eidx[i];
        int pos = atomicAdd(&cursor[s], 1);
        edge_order[pos] = i;
    }
}

// ---------------- node gather: accumulate all messages for one node, no atomics ----------------
__global__ __launch_bounds__(256) void node_gather(
    const float* __restrict__ xsp,
    const float* __restrict__ rbf, const float* __restrict__ fcut,
    const float* __restrict__ rsh, const int* __restrict__ eidx,
    const float* __restrict__ Wr, const float* __restrict__ br,
    const float* __restrict__ so,
    const int* __restrict__ offsets, const int* __restrict__ edge_order,
    float* __restrict__ out_scalar, float* __restrict__ out_sph) {
    __shared__ float Wr_s[NUM_BASIS * HIDDEN];   // 46080 B; reused as merge buffer
    __shared__ float fo[2][HIDDEN];
    __shared__ float rbf_s[2][NUM_BASIS];
    const int tid  = threadIdx.x;
    const int half = tid >> 7;       // which edge of the pair
    const int j0   = tid & 127;
    const int n    = blockIdx.x;

    for (int i = tid; i < NUM_BASIS * HIDDEN; i += 256) Wr_s[i] = Wr[i];

    const int beg = offsets[n];
    const int end = offsets[n + 1];

    float accS  = 0.f;                       // scalar message, index j0
    float accD0 = 0.f, accD1 = 0.f, accD2 = 0.f, accD3 = 0.f;  // sph d = j0 + 128c

    __syncthreads();

    for (int base = beg; base < end; base += 2) {
        const int idx = base + half;
        const bool active = idx < end;
        int e = 0, dst = 0; float fc = 0.f;
        if (active) {
            e   = edge_order[idx];
            dst = eidx[N_EDGES + e];
            fc  = fcut[e];
        }
        if (active && j0 < NUM_BASIS) rbf_s[half][j0] = rbf[(size_t)e * NUM_BASIS + j0];
        __syncthreads();

        if (active) {
            const float* sor = so + (size_t)dst * HIDDEN;
            #pragma unroll
            for (int c = 0; c < 5; ++c) {
                int j = j0 + 128 * c;
                if (j < HIDDEN) {
                    float a = br[j];
                    #pragma unroll
                    for (int k = 0; k < NUM_BASIS; ++k)
                        a = fmaf(rbf_s[half][k], Wr_s[k * HIDDEN + j], a);
                    fo[half][j] = a * fc * sor[j];
                }
            }
        }
        __syncthreads();

        if (active) {
            accS += fo[half][2 * NUM_IRREPS + j0];
            const float* xr = xsp + (size_t)dst * SPH_DIM;
            const float* rr = rsh + (size_t)e * SPH_DIM;
            {   // d in [0,128): g = d
                int d = j0; int g = d;
                accD0 = fmaf(xr[d], fo[half][g], fmaf(rr[d], fo[half][NUM_IRREPS + g], accD0));
            }
            {   // d in [128,256): g = 128 + (d-128)/3
                int d = j0 + 128; int g = 128 + (d - 128) / 3;
                accD1 = fmaf(xr[d], fo[half][g], fmaf(rr[d], fo[half][NUM_IRREPS + g], accD1));
            }
            {   // d in [256,384)
                int d = j0 + 256;
                int g = (d < 320) ? (128 + (d - 128) / 3) : (192 + (d - 320) / 5);
                accD2 = fmaf(xr[d], fo[half][g], fmaf(rr[d], fo[half][NUM_IRREPS + g], accD2));
            }
            {   // d in [384,480)
                int d = j0 + 384;
                if (d < SPH_DIM) {
                    int g = 192 + (d - 320) / 5;
                    accD3 = fmaf(xr[d], fo[half][g], fmaf(rr[d], fo[half][NUM_IRREPS + g], accD3));
                }
            }
        }
    }
    __syncthreads();

    // merge the two halves via the (now free) Wr_s buffer: 2 x 608 floats
    float* mb = Wr_s + half * 608;
    mb[j0]             = accS;
    mb[128 + j0]       = accD0;
    mb[128 + j0 + 128] = accD1;
    mb[128 + j0 + 256] = accD2;
    if (j0 < 96) mb[128 + j0 + 384] = accD3;
    __syncthreads();

    for (int i = tid; i < NODE_DIM + SPH_DIM; i += 256) {
        float v = Wr_s[i] + Wr_s[608 + i];
        if (i < NODE_DIM) out_scalar[(size_t)n * NODE_DIM + i] += v;
        else              out_sph[(size_t)n * SPH_DIM + (i - NODE_DIM)] += v;
    }
}

extern "C" void kernel_launch(void* const* d_in, const int* in_sizes, int n_in,
                              void* d_out, int out_size, void* d_ws, size_t ws_size,
                              hipStream_t stream) {
    const float* x_scalar    = (const float*)d_in[0];
    const float* x_spherical = (const float*)d_in[1];
    const float* rbf         = (const float*)d_in[2];
    const float* fcut        = (const float*)d_in[3];
    const float* rsh         = (const float*)d_in[4];
    const int*   eidx        = (const int*)d_in[5];
    const float* W1          = (const float*)d_in[6];
    const float* b1          = (const float*)d_in[7];
    const float* W2          = (const float*)d_in[8];
    const float* b2          = (const float*)d_in[9];
    const float* Wr          = (const float*)d_in[10];
    const float* br          = (const float*)d_in[11];

    float* out        = (float*)d_out;
    float* out_scalar = out;                                   // (N_NODES, 128)
    float* out_sph    = out + (size_t)N_NODES * NODE_DIM;      // (N_NODES, 480)

    // workspace layout (floats/ints, all 4B-aligned)
    float* scalar_out = (float*)d_ws;                          // 10000*576 floats
    int*   counts     = (int*)(scalar_out + (size_t)N_NODES * HIDDEN);   // 10000
    int*   offsets    = counts + N_NODES;                      // 10001
    int*   cursor     = offsets + N_NODES + 1;                 // 10000
    int*   edge_order = cursor + N_NODES;                      // 160000

    init_out<<<2048, 256, 0, stream>>>(x_scalar, x_spherical, out, counts);
    hist_kernel<<<(N_EDGES + 255) / 256, 256, 0, stream>>>(eidx, counts);
    scan_kernel<<<1, 1024, 0, stream>>>(counts, offsets, cursor);
    scatter_kernel<<<(N_EDGES + 255) / 256, 256, 0, stream>>>(eidx, cursor, edge_order);
    node_mlp<<<(N_NODES + NPB - 1) / NPB, 128, 0, stream>>>(x_scalar, W1, b1, W2, b2, scalar_out);
    node_gather<<<N_NODES, 256, 0, stream>>>(x_spherical, rbf, fcut, rsh, eidx,
                                             Wr, br, scalar_out, offsets, edge_order,
                                             out_scalar, out_sph);
}

// Round 3
// 334.886 us; speedup vs baseline: 1.6364x; 1.4941x over previous
//
#include <hip/hip_runtime.h>

#define NODE_DIM 128
#define NUM_IRREPS 224
#define SPH_DIM 480
#define HIDDEN 576   // NODE_DIM + 2*NUM_IRREPS
#define NUM_BASIS 20
#define N_NODES 10000
#define N_EDGES 160000
#define NPB 4        // nodes per block in node MLP

// ---------------- init: d_out = concat(x_scalar, x_spherical); zero counts ----------------
__global__ void init_out(const float* __restrict__ xs,
                         const float* __restrict__ xsp,
                         float* __restrict__ out,
                         int* __restrict__ counts) {
    const int stride = gridDim.x * blockDim.x;
    const int t0 = blockIdx.x * blockDim.x + threadIdx.x;
    for (int i = t0; i < N_NODES * NODE_DIM; i += stride) out[i] = xs[i];
    float* o2 = out + (size_t)N_NODES * NODE_DIM;
    for (int i = t0; i < N_NODES * SPH_DIM; i += stride) o2[i] = xsp[i];
    for (int i = t0; i < N_NODES; i += stride) counts[i] = 0;
}

// ---------------- node MLP: scalar_out = silu(x@W1+b1)@W2+b2 ----------------
__global__ __launch_bounds__(128) void node_mlp(
    const float* __restrict__ x,
    const float* __restrict__ W1, const float* __restrict__ b1,
    const float* __restrict__ W2, const float* __restrict__ b2,
    float* __restrict__ so) {
    __shared__ float xs[NPB][NODE_DIM];
    __shared__ float hs[NPB][NODE_DIM];
    const int tid = threadIdx.x;
    const int n0 = blockIdx.x * NPB;

    #pragma unroll
    for (int n = 0; n < NPB; ++n) {
        int node = n0 + n;
        xs[n][tid] = (node < N_NODES) ? x[(size_t)node * NODE_DIM + tid] : 0.f;
    }
    __syncthreads();

    float acc[NPB];
    #pragma unroll
    for (int n = 0; n < NPB; ++n) acc[n] = b1[tid];
    for (int k = 0; k < NODE_DIM; ++k) {
        float w = W1[k * NODE_DIM + tid];
        #pragma unroll
        for (int n = 0; n < NPB; ++n) acc[n] = fmaf(xs[n][k], w, acc[n]);
    }
    #pragma unroll
    for (int n = 0; n < NPB; ++n) {
        float v = acc[n];
        hs[n][tid] = v / (1.f + __expf(-v));
    }
    __syncthreads();

    for (int j = tid; j < HIDDEN; j += 128) {
        float a2[NPB];
        #pragma unroll
        for (int n = 0; n < NPB; ++n) a2[n] = b2[j];
        for (int k = 0; k < NODE_DIM; ++k) {
            float w = W2[k * HIDDEN + j];
            #pragma unroll
            for (int n = 0; n < NPB; ++n) a2[n] = fmaf(hs[n][k], w, a2[n]);
        }
        #pragma unroll
        for (int n = 0; n < NPB; ++n) {
            int node = n0 + n;
            if (node < N_NODES) so[(size_t)node * HIDDEN + j] = a2[n];
        }
    }
}

// ---------------- CSR build: histogram / scan / scatter ----------------
__global__ __launch_bounds__(256) void hist_kernel(const int* __restrict__ eidx,
                                                   int* __restrict__ counts) {
    int i = blockIdx.x * blockDim.x + threadIdx.x;
    if (i < N_EDGES) atomicAdd(&counts[eidx[i]], 1);   // bucket by src = edge_index[0]
}

__global__ __launch_bounds__(1024) void scan_kernel(const int* __restrict__ counts,
                                                    int* __restrict__ offsets,
                                                    int* __restrict__ cursor) {
    __shared__ int s[1024];
    const int tid = threadIdx.x;
    int vals[10];
    int run = 0;
    #pragma unroll
    for (int i = 0; i < 10; ++i) {
        int idx = tid * 10 + i;
        int c = (idx < N_NODES) ? counts[idx] : 0;
        vals[i] = run;
        run += c;
    }
    s[tid] = run;
    __syncthreads();
    for (int off = 1; off < 1024; off <<= 1) {
        int t = (tid >= off) ? s[tid - off] : 0;
        __syncthreads();
        if (tid >= off) s[tid] += t;
        __syncthreads();
    }
    int base = (tid > 0) ? s[tid - 1] : 0;
    #pragma unroll
    for (int i = 0; i < 10; ++i) {
        int idx = tid * 10 + i;
        if (idx < N_NODES) {
            int v = base + vals[i];
            offsets[idx] = v;
            cursor[idx] = v;
        }
    }
    if (tid == 1023) offsets[N_NODES] = s[1023];
}

__global__ __launch_bounds__(256) void scatter_kernel(const int* __restrict__ eidx,
                                                      int* __restrict__ cursor,
                                                      int* __restrict__ edge_order) {
    int i = blockIdx.x * blockDim.x + threadIdx.x;
    if (i < N_EDGES) {
        int s = eidx[i];
        int pos = atomicAdd(&cursor[s], 1);
        edge_order[pos] = i;
    }
}

// ---------------- node gather: one block per node, one irrep-role per thread ----------------
// Roles: t<224 -> irrep r=t. t in [224,256) -> helper: takes tail (p=3,4) of the
// 5-element group of irrep r=t-32 (duplicating that irrep's filter columns).
// Each thread keeps its filter columns of Wr in REGISTERS; no LDS, no barriers
// in the edge loop; edge metadata + rbf software-prefetched one edge ahead.
__global__ __launch_bounds__(256) void node_gather(
    const float* __restrict__ xsp,
    const float* __restrict__ rbf, const float* __restrict__ fcut,
    const float* __restrict__ rsh, const int* __restrict__ eidx,
    const float* __restrict__ Wr, const float* __restrict__ br,
    const float* __restrict__ so,
    const int* __restrict__ offsets, const int* __restrict__ edge_order,
    float* __restrict__ out_scalar, float* __restrict__ out_sph)
{
    const int t = threadIdx.x;
    const int n = blockIdx.x;
    const bool dup  = (t >= 224);
    const int  r    = dup ? (t - 32) : t;       // irrep index in [0,224)
    const int  j0   = r;                        // gate_state column
    const int  j1   = NUM_IRREPS + r;           // gate_edge column
    const bool has2 = (t < 128);                // owns a message_scalar column
    const int  j2   = 2 * NUM_IRREPS + t;

    // spherical elements owned by this thread: d0 .. d0+nd-1
    int nd, d0;
    if (t < 128)      { nd = 1; d0 = t; }
    else if (t < 192) { nd = 3; d0 = 128 + (t - 128) * 3; }
    else if (t < 224) { nd = 3; d0 = 320 + (t - 192) * 5; }
    else              { nd = 2; d0 = 320 + (t - 224) * 5 + 3; }

    // preload this thread's Wr columns into registers (fully unrolled -> regs)
    float wr0[NUM_BASIS], wr1[NUM_BASIS], wr2[NUM_BASIS];
    #pragma unroll
    for (int k = 0; k < NUM_BASIS; ++k) {
        wr0[k] = Wr[k * HIDDEN + j0];
        wr1[k] = Wr[k * HIDDEN + j1];
        wr2[k] = has2 ? Wr[k * HIDDEN + j2] : 0.f;
    }
    const float br0 = br[j0], br1 = br[j1], br2 = has2 ? br[j2] : 0.f;

    const int beg = offsets[n];
    const int end = offsets[n + 1];

    float accS = 0.f, accD0 = 0.f, accD1 = 0.f, accD2 = 0.f;

    if (beg < end) {
        // prefetch first edge
        int   e   = edge_order[beg];
        int   dst = eidx[N_EDGES + e];
        float fc  = fcut[e];
        const float4* r4 = (const float4*)(rbf + (size_t)e * NUM_BASIS);
        float4 q0 = r4[0], q1 = r4[1], q2 = r4[2], q3 = r4[3], q4 = r4[4];

        for (int idx = beg; idx < end; ++idx) {
            const int   ce   = e;
            const int   cdst = dst;
            const float cfc  = fc;
            const float rb[NUM_BASIS] = {q0.x,q0.y,q0.z,q0.w, q1.x,q1.y,q1.z,q1.w,
                                         q2.x,q2.y,q2.z,q2.w, q3.x,q3.y,q3.z,q3.w,
                                         q4.x,q4.y,q4.z,q4.w};
            // prefetch next edge's metadata + rbf
            if (idx + 1 < end) {
                e   = edge_order[idx + 1];
                dst = eidx[N_EDGES + e];
                fc  = fcut[e];
                r4  = (const float4*)(rbf + (size_t)e * NUM_BASIS);
                q0 = r4[0]; q1 = r4[1]; q2 = r4[2]; q3 = r4[3]; q4 = r4[4];
            }

            float a0 = br0, a1 = br1;
            #pragma unroll
            for (int k = 0; k < NUM_BASIS; ++k) {
                a0 = fmaf(rb[k], wr0[k], a0);
                a1 = fmaf(rb[k], wr1[k], a1);
            }
            const float* sod = so + (size_t)cdst * HIDDEN;
            const float fo0 = a0 * cfc * sod[j0];
            const float fo1 = a1 * cfc * sod[j1];
            if (has2) {   // wave-uniform branch (t<128 spans waves 0,1)
                float a2 = br2;
                #pragma unroll
                for (int k = 0; k < NUM_BASIS; ++k) a2 = fmaf(rb[k], wr2[k], a2);
                accS = fmaf(a2 * cfc, sod[j2], accS);
            }
            const float* xd = xsp + (size_t)cdst * SPH_DIM + d0;
            const float* rd = rsh + (size_t)ce  * SPH_DIM + d0;
            accD0 = fmaf(xd[0], fo0, fmaf(rd[0], fo1, accD0));
            if (nd > 1) accD1 = fmaf(xd[1], fo0, fmaf(rd[1], fo1, accD1));
            if (nd > 2) accD2 = fmaf(xd[2], fo0, fmaf(rd[2], fo1, accD2));
        }
    }

    if (t < 128) out_scalar[(size_t)n * NODE_DIM + t] += accS;
    float* od = out_sph + (size_t)n * SPH_DIM + d0;
    od[0] += accD0;
    if (nd > 1) od[1] += accD1;
    if (nd > 2) od[2] += accD2;
}

extern "C" void kernel_launch(void* const* d_in, const int* in_sizes, int n_in,
                              void* d_out, int out_size, void* d_ws, size_t ws_size,
                              hipStream_t stream) {
    const float* x_scalar    = (const float*)d_in[0];
    const float* x_spherical = (const float*)d_in[1];
    const float* rbf         = (const float*)d_in[2];
    const float* fcut        = (const float*)d_in[3];
    const float* rsh         = (const float*)d_in[4];
    const int*   eidx        = (const int*)d_in[5];
    const float* W1          = (const float*)d_in[6];
    const float* b1          = (const float*)d_in[7];
    const float* W2          = (const float*)d_in[8];
    const float* b2          = (const float*)d_in[9];
    const float* Wr          = (const float*)d_in[10];
    const float* br          = (const float*)d_in[11];

    float* out        = (float*)d_out;
    float* out_scalar = out;                                   // (N_NODES, 128)
    float* out_sph    = out + (size_t)N_NODES * NODE_DIM;      // (N_NODES, 480)

    // workspace layout
    float* scalar_out = (float*)d_ws;                          // 10000*576 floats
    int*   counts     = (int*)(scalar_out + (size_t)N_NODES * HIDDEN);   // 10000
    int*   offsets    = counts + N_NODES;                      // 10001
    int*   cursor     = offsets + N_NODES + 1;                 // 10000
    int*   edge_order = cursor + N_NODES;                      // 160000

    init_out<<<2048, 256, 0, stream>>>(x_scalar, x_spherical, out, counts);
    hist_kernel<<<(N_EDGES + 255) / 256, 256, 0, stream>>>(eidx, counts);
    scan_kernel<<<1, 1024, 0, stream>>>(counts, offsets, cursor);
    scatter_kernel<<<(N_EDGES + 255) / 256, 256, 0, stream>>>(eidx, cursor, edge_order);
    node_mlp<<<(N_NODES + NPB - 1) / NPB, 128, 0, stream>>>(x_scalar, W1, b1, W2, b2, scalar_out);
    node_gather<<<N_NODES, 256, 0, stream>>>(x_spherical, rbf, fcut, rsh, eidx,
                                             Wr, br, scalar_out, offsets, edge_order,
                                             out_scalar, out_sph);
}